// Round 12
// baseline (152.537 us; speedup 1.0000x reference)
//
#include <hip/hip_runtime.h>
#include <hip/hip_bf16.h>
#include <math.h>

#define N_NODES 10000
#define N_EDGES 100000
#define NCH 64
#define NSPEC 10
#define EBLK 391   // (N_EDGES+255)/256
#define NBLK 40    // (N_NODES+255)/256

typedef __attribute__((ext_vector_type(8))) short short8v;
typedef __attribute__((ext_vector_type(4))) float f32x4;

static __device__ __forceinline__ unsigned short f2bf(float f){
  unsigned u = __float_as_uint(f);
  u += 0x7fff + ((u >> 16) & 1);          // round-to-nearest-even
  return (unsigned short)(u >> 16);
}
static __device__ __forceinline__ float bf2f(unsigned u){
  return __uint_as_float(u << 16);
}
static __device__ __forceinline__ unsigned packbf(float a, float b){
  return (unsigned)f2bf(a) | ((unsigned)f2bf(b) << 16);
}

// ---------- CSR count (edges) + species histogram ----------
__global__ void k_count(const int* __restrict__ recv, int* __restrict__ cnt,
                        const int* __restrict__ species, int* __restrict__ spcnt){
  int b = blockIdx.x;
  if (b < EBLK){
    int i = b*blockDim.x + threadIdx.x;
    if (i < N_EDGES) atomicAdd(&cnt[recv[i]], 1);
  } else {
    int j = (b-EBLK)*blockDim.x + threadIdx.x;
    if (j < N_NODES) atomicAdd(&spcnt[species[j]], 1);
  }
}

// ---------- fused prologue: zero cursor+histo | transposes | h1(bf16) | bf16 B-fragments ----------
__global__ __launch_bounds__(256) void k_pre(
  int* __restrict__ cursor, int* __restrict__ spcnt, int* __restrict__ spcur,
  const float* __restrict__ sel, const float* __restrict__ resw,
  float* __restrict__ selT, float* __restrict__ resT,
  const int* __restrict__ species, const float* __restrict__ embedW,
  const float* __restrict__ linup, unsigned short* __restrict__ h1p,
  const float* __restrict__ rW2a, const float* __restrict__ rW2b,
  unsigned short* __restrict__ wfrag)
{
  int b = blockIdx.x;
  int tid = threadIdx.x;
  if (b < 40){                                  // zero cursor (10000 ints) + histo
    int i = b*256 + tid;
    if (i < N_NODES) cursor[i] = 0;
    if (b == 0 && tid < NSPEC){ spcnt[tid] = 0; spcur[tid] = 0; }
  } else if (b < 200){                          // selT/resT transpose (40960 elems)
    int i = (b-40)*256 + tid;
    int s = i >> 12, r = i & 4095, d = r >> 6, c = r & 63;
    int src = s*4096 + c*64 + d;
    selT[i] = sel[src];
    resT[i] = resw[src];
  } else if (b < 2700){                         // h1 = embed[species] @ l1_lin_up (bf16)
    int w = ((b-200)*256 + tid) >> 6;           // 2500 blocks * 4 = 10000
    int lane = tid & 63;
    int sp = __builtin_amdgcn_readfirstlane(species[w]);
    const float* x0 = embedW + sp*NCH;
    float acc = 0.f;
    #pragma unroll
    for (int d = 0; d < NCH; d++) acc += x0[d] * linup[d*NCH + lane];
    h1p[w*NCH + lane] = f2bf(acc);
  } else {                                      // bf16 B-fragments (12288 shorts)
    int i = (b-2700)*256 + tid;
    int slot = i >> 9;                          // 0..23
    int rem  = i & 511;
    int lane = rem >> 3, j = rem & 7;
    int cl = lane & 15, hb = (lane >> 4)*8;
    float v;
    if (slot < 16){
      int t = slot >> 2, f = slot & 3;
      int colofs = f >> 1, off = (f & 1)*32;
      v = rW2a[(hb + off + j)*256 + 4*(t*16 + cl) + colofs];
    } else {
      int s2 = slot - 16;
      int t = s2 >> 1, f = s2 & 1;
      int off = f*32;
      v = rW2b[(hb + off + j)*256 + 4*(t*16 + cl)];
    }
    wfrag[i] = f2bf(v);
  }
}

// ---------- block 0: CSR scan + species prefix | blocks 1..: MFMA radial GEMM ----------
__global__ __launch_bounds__(256) void k_scanrw(
    int* __restrict__ cnt_cursor, int* __restrict__ starts,
    int* __restrict__ spcnt, int* __restrict__ spcur,
    const float* __restrict__ ev,
    const float* __restrict__ rW1a, const float* __restrict__ rW1b,
    const unsigned short* __restrict__ wfrag,
    unsigned* __restrict__ rw12p, unsigned short* __restrict__ rwBp,
    float4* __restrict__ shu)
{
  __shared__ short s_hid1[64*72];      // [e][h] bf16, row stride 72 (144B)
  __shared__ short s_hid2[64*72];

  int tid = threadIdx.x;

  if (blockIdx.x == 0){
    // coarsened scan: 256 threads, 40 nodes each
    int* stot = (int*)s_hid1;
    int base = tid*40;
    int loc[40];
    int sum = 0;
    #pragma unroll
    for (int j = 0; j < 40; j++){
      int i = base + j;
      int v = (i < N_NODES) ? cnt_cursor[i] : 0;
      loc[j] = sum; sum += v;
    }
    stot[tid] = sum;
    __syncthreads();
    for (int off = 1; off < 256; off <<= 1){
      int t = (tid >= off) ? stot[tid-off] : 0;
      __syncthreads();
      stot[tid] += t;
      __syncthreads();
    }
    int excl = stot[tid] - sum;
    #pragma unroll
    for (int j = 0; j < 40; j++){
      int i = base + j;
      if (i < N_NODES){ int st = excl + loc[j]; starts[i] = st; cnt_cursor[i] = st; }
    }
    if (tid == 255) starts[N_NODES] = stot[255];
    if (tid == 0){
      int run = 0;
      #pragma unroll
      for (int s = 0; s < NSPEC; s++){ int c = spcnt[s]; spcur[s] = run; run += c; }
    }
    return;
  }

  int e0 = (blockIdx.x-1)*64;
  int lane = tid & 63;
  int w = __builtin_amdgcn_readfirstlane(tid >> 6);    // wave id 0..3

  // geometry + bessel for edge e0+lane (4-way redundant across waves)
  int e = e0 + lane;
  bool act = (e < N_EDGES);
  float ex = 0.f, ey = 0.f, ez = 1.f;
  if (act){ ex = ev[e*3+0]; ey = ev[e*3+1]; ez = ev[e*3+2]; }
  float r = sqrtf(ex*ex + ey*ey + ez*ez + 1e-12f);
  float rinv = 1.0f / r;
  float u = r * 0.2f;
  float env = 0.f;
  if (u < 1.f){ float om = 1.f - u; env = om*om*(1.f + 2.f*u); }
  float pref = 0.6324555320336759f * rinv * env;       // sqrt(2/5)
  float rad[8];
  #pragma unroll
  for (int b = 0; b < 8; b++)
    rad[b] = pref * __sinf((float)(b+1) * 3.14159265358979f * u);
  if (w == 0 && act) shu[e] = make_float4(ex*rinv, ey*rinv, ez*rinv, 0.f);

  // hid for both layers (16 h per wave each), one barrier total
  {
    short8v hv0, hv1, gv0, gv1;
    #pragma unroll
    for (int j = 0; j < 16; j++){
      int h = w*16 + j;
      float a1 = 0.f, a2 = 0.f;
      #pragma unroll
      for (int b = 0; b < 8; b++){
        a1 += rad[b] * rW1a[b*64 + h];               // uniform -> s_load
        a2 += rad[b] * rW1b[b*64 + h];
      }
      float hd1 = a1 / (1.f + __expf(-a1));
      float hd2 = a2 / (1.f + __expf(-a2));
      unsigned short q1 = f2bf(hd1), q2 = f2bf(hd2);
      if (j < 8){ hv0[j] = (short)q1; gv0[j] = (short)q2; }
      else      { hv1[j-8] = (short)q1; gv1[j-8] = (short)q2; }
    }
    *(short8v*)&s_hid1[lane*72 + w*16]     = hv0;
    *(short8v*)&s_hid1[lane*72 + w*16 + 8] = hv1;
    *(short8v*)&s_hid2[lane*72 + w*16]     = gv0;
    *(short8v*)&s_hid2[lane*72 + w*16 + 8] = gv1;
  }
  __syncthreads();

  int cl = lane & 15;                 // col within 16-tile
  int hb = (lane >> 4) * 8;           // k base within 32-step
  int rowq = (lane >> 4) * 4;         // D row base

  short8v a0  = *(short8v*)&s_hid1[(w*16 + cl)*72 + hb];
  short8v a1  = *(short8v*)&s_hid1[(w*16 + cl)*72 + hb + 32];
  short8v c0f = *(short8v*)&s_hid2[(w*16 + cl)*72 + hb];
  short8v c1f = *(short8v*)&s_hid2[(w*16 + cl)*72 + hb + 32];

  const short8v* wf1 = (const short8v*)wfrag;           // 16*64 frags
  const short8v* wf2 = ((const short8v*)wfrag) + 1024;  // 8*64 frags

  f32x4 ax[4], ay[4], bc[4];
  #pragma unroll
  for (int t = 0; t < 4; t++){
    ax[t] = (f32x4)(0.f); ay[t] = (f32x4)(0.f); bc[t] = (f32x4)(0.f);
  }
  #pragma unroll
  for (int t = 0; t < 4; t++){
    short8v bx0 = wf1[(t*4+0)*64 + lane];   // coalesced 16B/lane
    short8v bx1 = wf1[(t*4+1)*64 + lane];
    short8v by0 = wf1[(t*4+2)*64 + lane];
    short8v by1 = wf1[(t*4+3)*64 + lane];
    short8v b20 = wf2[(t*2+0)*64 + lane];
    short8v b21 = wf2[(t*2+1)*64 + lane];
    ax[t] = __builtin_amdgcn_mfma_f32_16x16x32_bf16(a0, bx0, ax[t], 0, 0, 0);
    ax[t] = __builtin_amdgcn_mfma_f32_16x16x32_bf16(a1, bx1, ax[t], 0, 0, 0);
    ay[t] = __builtin_amdgcn_mfma_f32_16x16x32_bf16(a0, by0, ay[t], 0, 0, 0);
    ay[t] = __builtin_amdgcn_mfma_f32_16x16x32_bf16(a1, by1, ay[t], 0, 0, 0);
    bc[t] = __builtin_amdgcn_mfma_f32_16x16x32_bf16(c0f, b20, bc[t], 0, 0, 0);
    bc[t] = __builtin_amdgcn_mfma_f32_16x16x32_bf16(c1f, b21, bc[t], 0, 0, 0);
  }
  #pragma unroll
  for (int t = 0; t < 4; t++){
    #pragma unroll
    for (int i = 0; i < 4; i++){
      int er = e0 + w*16 + rowq + i;
      if (er < N_EDGES){
        rw12p[(size_t)er*64 + t*16 + cl] = packbf(ax[t][i], ay[t][i]);
        rwBp [(size_t)er*64 + t*16 + cl] = f2bf(bc[t][i]);
      }
    }
  }
}

// ---------- CSR fill (edges) + species-sorted node list ----------
__global__ void k_fill(const int* __restrict__ recv, int* __restrict__ cursor,
                       int* __restrict__ elist,
                       const int* __restrict__ species, int* __restrict__ spcur,
                       int* __restrict__ nsort){
  int b = blockIdx.x;
  if (b < EBLK){
    int i = b*blockDim.x + threadIdx.x;
    if (i < N_EDGES){ int pos = atomicAdd(&cursor[recv[i]], 1); elist[pos] = i; }
  } else {
    int j = (b-EBLK)*blockDim.x + threadIdx.x;
    if (j < N_NODES){ int pos = atomicAdd(&spcur[species[j]], 1); nsort[pos] = j; }
  }
}

// ---------- pass-1 gather + node transforms (species-sorted, 4-deep prefetch) ----------
__global__ __launch_bounds__(256) void k_node1(
  const int* __restrict__ senders, const int* __restrict__ species,
  const int* __restrict__ starts, const int* __restrict__ elist,
  const int* __restrict__ nsort,
  const float4* __restrict__ shu,
  const unsigned* __restrict__ rw12p, const unsigned short* __restrict__ h1p,
  const float* __restrict__ selT,
  const float* __restrict__ pw, const float* __restrict__ uwv,
  const float* __restrict__ row,
  const float* __restrict__ linup2, const float* __restrict__ resT,
  float* __restrict__ out,
  uint2* __restrict__ outvp, float* __restrict__ reso)
{
  int lane  = threadIdx.x & 63;
  int wslot = threadIdx.x >> 6;
  int n = __builtin_amdgcn_readfirstlane(nsort[blockIdx.x*4 + wslot]);
  __shared__ float4 sacc[4][64];

  int s0 = __builtin_amdgcn_readfirstlane(starts[n]);
  int s1 = __builtin_amdgcn_readfirstlane(starts[n+1]);
  int sp = __builtin_amdgcn_readfirstlane(species[n]);

  float acc0 = 0.f, acc1 = 0.f, acc2 = 0.f, acc3 = 0.f;
  for (int base = s0; base < s1; base += 64){
    int m = min(64, s1 - base);
    int e_l = 0, snd_l = 0;
    if (lane < m){
      e_l   = elist[base + lane];
      snd_l = senders[e_l];
    }
    for (int t = 0; t < m; t += 4){
      int i0 = t;
      int i1 = min(t+1, m-1), i2 = min(t+2, m-1), i3 = min(t+3, m-1);
      float w1 = (t+1 < m) ? 1.f : 0.f;
      float w2 = (t+2 < m) ? 1.f : 0.f;
      float w3 = (t+3 < m) ? 1.f : 0.f;
      int e0i = __builtin_amdgcn_readfirstlane(__shfl(e_l, i0, 64));
      int s0i = __builtin_amdgcn_readfirstlane(__shfl(snd_l, i0, 64));
      int e1i = __builtin_amdgcn_readfirstlane(__shfl(e_l, i1, 64));
      int s1i = __builtin_amdgcn_readfirstlane(__shfl(snd_l, i1, 64));
      int e2i = __builtin_amdgcn_readfirstlane(__shfl(e_l, i2, 64));
      int s2i = __builtin_amdgcn_readfirstlane(__shfl(snd_l, i2, 64));
      int e3i = __builtin_amdgcn_readfirstlane(__shfl(e_l, i3, 64));
      int s3i = __builtin_amdgcn_readfirstlane(__shfl(snd_l, i3, 64));
      unsigned p0 = rw12p[(size_t)e0i*64 + lane];
      unsigned p1 = rw12p[(size_t)e1i*64 + lane];
      unsigned p2 = rw12p[(size_t)e2i*64 + lane];
      unsigned p3 = rw12p[(size_t)e3i*64 + lane];
      float h0 = bf2f(h1p[s0i*64 + lane]);
      float h1v = bf2f(h1p[s1i*64 + lane]) * w1;
      float h2v = bf2f(h1p[s2i*64 + lane]) * w2;
      float h3v = bf2f(h1p[s3i*64 + lane]) * w3;
      float4 v0 = shu[e0i];
      float4 v1 = shu[e1i];
      float4 v2 = shu[e2i];
      float4 v3 = shu[e3i];
      acc0 += bf2f(p0 & 0xffffu)*h0;  float m0 = bf2f(p0 >> 16)*h0;
      acc1 += m0*v0.x; acc2 += m0*v0.y; acc3 += m0*v0.z;
      acc0 += bf2f(p1 & 0xffffu)*h1v; float m1 = bf2f(p1 >> 16)*h1v;
      acc1 += m1*v1.x; acc2 += m1*v1.y; acc3 += m1*v1.z;
      acc0 += bf2f(p2 & 0xffffu)*h2v; float m2 = bf2f(p2 >> 16)*h2v;
      acc1 += m2*v2.x; acc2 += m2*v2.y; acc3 += m2*v2.z;
      acc0 += bf2f(p3 & 0xffffu)*h3v; float m3 = bf2f(p3 >> 16)*h3v;
      acc1 += m3*v3.x; acc2 += m3*v3.y; acc3 += m3*v3.z;
    }
  }
  const float c10 = 0.1f;                      // 1/AVG_NEIGH
  const float c13 = 0.17320508075688773f;      // sqrt(3)/10
  sacc[wslot][lane] = make_float4(acc0*c10, acc1*c13, acc2*c13, acc3*c13);
  asm volatile("s_waitcnt lgkmcnt(0)" ::: "memory");

  // feats[c,k] = sum_d selW[c,d] * agg[d,k]   (selT[sp] is L1-resident: species-sorted blocks)
  const float* selp = selT + sp*4096;
  float f0 = 0.f, f1 = 0.f, f2 = 0.f, f3 = 0.f;
  #pragma unroll 8
  for (int d = 0; d < 64; d++){
    float wv = selp[d*64 + lane];
    float4 a = sacc[wslot][d];
    f0 += wv*a.x; f1 += wv*a.y; f2 += wv*a.z; f3 += wv*a.w;
  }

  float s = f0;
  const float* pwp = pw  + sp*192;
  const float* uwp = uwv + sp*192;
  float pw0 = pwp[lane], pw1 = pwp[64+lane], pw2 = pwp[128+lane];
  float uw0 = uwp[lane], uw1 = uwp[64+lane], uw2 = uwp[128+lane];
  float ss = s*s;
  float o0  = pw0*s + pw1*ss + pw2*ss*s;
  float uco = uw0 + uw1*s + uw2*ss;

  // ro1 = sum_c o0[c]*row[c]
  float rv = o0 * row[lane];
  #pragma unroll
  for (int off = 32; off >= 1; off >>= 1) rv += __shfl_xor(rv, off, 64);
  if (lane == 0) out[n*2 + 0] = rv;

  // stage o0, compute h2 and res
  float* so = reinterpret_cast<float*>(&sacc[wslot][0]);
  asm volatile("s_waitcnt lgkmcnt(0)" ::: "memory");
  so[lane] = o0;
  asm volatile("s_waitcnt lgkmcnt(0)" ::: "memory");

  float hh = 0.f, rr = 0.f;
  const float* resp = resT + sp*4096;
  #pragma unroll 8
  for (int d = 0; d < 64; d++){
    float od = so[d];
    hh += od * linup2[d*64 + lane];
    rr += od * resp[d*64 + lane];
  }
  uint2 op;
  op.x = packbf(uco*f1, uco*f2);
  op.y = packbf(uco*f3, hh);
  outvp[n*64 + lane] = op;
  reso[n*64 + lane] = rr;
}

// ---------- pass-2 gather + readout (species-sorted, 4-deep prefetch) ----------
__global__ __launch_bounds__(256) void k_node2(
  const int* __restrict__ senders, const int* __restrict__ species,
  const int* __restrict__ starts, const int* __restrict__ elist,
  const int* __restrict__ nsort,
  const float4* __restrict__ shu,
  const unsigned short* __restrict__ rwBp,
  const uint2* __restrict__ outvp, const float* __restrict__ reso,
  const float* __restrict__ pw2,
  const float* __restrict__ roW1, const float* __restrict__ roW2,
  float* __restrict__ out)
{
  int lane  = threadIdx.x & 63;
  int wslot = threadIdx.x >> 6;
  int n = __builtin_amdgcn_readfirstlane(nsort[blockIdx.x*4 + wslot]);
  __shared__ float sout[4][64];

  int s0 = __builtin_amdgcn_readfirstlane(starts[n]);
  int s1 = __builtin_amdgcn_readfirstlane(starts[n+1]);
  int sp = __builtin_amdgcn_readfirstlane(species[n]);

  float acc = 0.f;
  for (int base = s0; base < s1; base += 64){
    int m = min(64, s1 - base);
    int e_l = 0, snd_l = 0;
    if (lane < m){
      e_l   = elist[base + lane];
      snd_l = senders[e_l];
    }
    for (int t = 0; t < m; t += 4){
      int i0 = t;
      int i1 = min(t+1, m-1), i2 = min(t+2, m-1), i3 = min(t+3, m-1);
      float w1 = (t+1 < m) ? 1.f : 0.f;
      float w2 = (t+2 < m) ? 1.f : 0.f;
      float w3 = (t+3 < m) ? 1.f : 0.f;
      int e0i = __builtin_amdgcn_readfirstlane(__shfl(e_l, i0, 64));
      int s0i = __builtin_amdgcn_readfirstlane(__shfl(snd_l, i0, 64));
      int e1i = __builtin_amdgcn_readfirstlane(__shfl(e_l, i1, 64));
      int s1i = __builtin_amdgcn_readfirstlane(__shfl(snd_l, i1, 64));
      int e2i = __builtin_amdgcn_readfirstlane(__shfl(e_l, i2, 64));
      int s2i = __builtin_amdgcn_readfirstlane(__shfl(snd_l, i2, 64));
      int e3i = __builtin_amdgcn_readfirstlane(__shfl(e_l, i3, 64));
      int s3i = __builtin_amdgcn_readfirstlane(__shfl(snd_l, i3, 64));
      float r0 = bf2f(rwBp[(size_t)e0i*64 + lane]);
      float r1 = bf2f(rwBp[(size_t)e1i*64 + lane]) * w1;
      float r2 = bf2f(rwBp[(size_t)e2i*64 + lane]) * w2;
      float r3 = bf2f(rwBp[(size_t)e3i*64 + lane]) * w3;
      uint2 o0v = outvp[s0i*64 + lane];
      uint2 o1v = outvp[s1i*64 + lane];
      uint2 o2v = outvp[s2i*64 + lane];
      uint2 o3v = outvp[s3i*64 + lane];
      float4 v0 = shu[e0i];
      float4 v1 = shu[e1i];
      float4 v2 = shu[e2i];
      float4 v3 = shu[e3i];
      acc += r0 * (bf2f(o0v.y >> 16) + bf2f(o0v.x & 0xffffu)*v0.x
                   + bf2f(o0v.x >> 16)*v0.y + bf2f(o0v.y & 0xffffu)*v0.z);
      acc += r1 * (bf2f(o1v.y >> 16) + bf2f(o1v.x & 0xffffu)*v1.x
                   + bf2f(o1v.x >> 16)*v1.y + bf2f(o1v.y & 0xffffu)*v1.z);
      acc += r2 * (bf2f(o2v.y >> 16) + bf2f(o2v.x & 0xffffu)*v2.x
                   + bf2f(o2v.x >> 16)*v2.y + bf2f(o2v.y & 0xffffu)*v2.z);
      acc += r3 * (bf2f(o3v.y >> 16) + bf2f(o3v.x & 0xffffu)*v3.x
                   + bf2f(o3v.x >> 16)*v3.y + bf2f(o3v.y & 0xffffu)*v3.z);
    }
  }
  float s2 = acc * 0.1f;
  const float* p2 = pw2 + sp*192;
  float q0 = p2[lane], q1 = p2[64+lane], q2 = p2[128+lane];
  float s2s = s2*s2;
  float o2 = q0*s2 + q1*s2s + q2*s2s*s2 + reso[n*64 + lane];

  sout[wslot][lane] = o2;
  asm volatile("s_waitcnt lgkmcnt(0)" ::: "memory");

  // ro2 = silu(out2 @ roW1) @ roW2
  int j = lane & 15, g = lane >> 4;
  float qp = 0.f;
  #pragma unroll
  for (int t = 0; t < 16; t++){
    int c = g*16 + t;
    qp += sout[wslot][c] * roW1[c*16 + j];
  }
  qp += __shfl_xor(qp, 16, 64);
  qp += __shfl_xor(qp, 32, 64);
  float sil = qp / (1.f + __expf(-qp));
  float contrib = sil * roW2[j];
  contrib += __shfl_xor(contrib, 1, 64);
  contrib += __shfl_xor(contrib, 2, 64);
  contrib += __shfl_xor(contrib, 4, 64);
  contrib += __shfl_xor(contrib, 8, 64);
  if (lane == 0) out[n*2 + 1] = contrib;
}

extern "C" void kernel_launch(void* const* d_in, const int* in_sizes, int n_in,
                              void* d_out, int out_size, void* d_ws, size_t ws_size,
                              hipStream_t stream)
{
  const float* ev     = (const float*)d_in[0];
  const int*   spec   = (const int*)  d_in[1];
  const int*   send   = (const int*)  d_in[2];
  const int*   recv   = (const int*)  d_in[3];
  const float* embedW = (const float*)d_in[4];
  const float* l1_lin = (const float*)d_in[5];
  const float* l1_rW1 = (const float*)d_in[6];
  const float* l1_rW2 = (const float*)d_in[7];
  const float* l1_sel = (const float*)d_in[8];
  const float* l1_pw  = (const float*)d_in[9];
  const float* l1_uw  = (const float*)d_in[10];
  const float* l1_row = (const float*)d_in[11];
  const float* l2_lin = (const float*)d_in[12];
  const float* l2_rW1 = (const float*)d_in[13];
  const float* l2_rW2 = (const float*)d_in[14];
  const float* l2_res = (const float*)d_in[15];
  const float* l2_pw  = (const float*)d_in[16];
  const float* l2_roW1= (const float*)d_in[17];
  const float* l2_roW2= (const float*)d_in[18];
  float* out = (float*)d_out;

  char* w = (char*)d_ws;
  unsigned*       rw12p = (unsigned*)w;       w += (size_t)N_EDGES*64*4;  // 25.6 MB
  unsigned short* rwBp  = (unsigned short*)w; w += (size_t)N_EDGES*64*2;  // 12.8 MB
  unsigned short* h1p   = (unsigned short*)w; w += (size_t)N_NODES*64*2;  // 1.28 MB
  uint2*  outvp = (uint2*)w;  w += (size_t)N_NODES*64*8;                  // 5.12 MB
  float*  reso  = (float*)w;  w += (size_t)N_NODES*64*4;
  float*  selT  = (float*)w;  w += (size_t)NSPEC*4096*4;
  float*  resT  = (float*)w;  w += (size_t)NSPEC*4096*4;
  float4* shu   = (float4*)w; w += (size_t)N_EDGES*16;
  unsigned short* wfrag = (unsigned short*)w; w += 12288*2;
  int* starts = (int*)w;      w += (size_t)(N_NODES+1)*4;
  int* cursor = (int*)w;      w += (size_t)N_NODES*4;
  int* elist  = (int*)w;      w += (size_t)N_EDGES*4;
  int* nsort  = (int*)w;      w += (size_t)N_NODES*4;
  int* spcnt  = (int*)w;      w += 16*4;
  int* spcur  = (int*)w;      w += 16*4;

  k_pre  <<<2748, 256, 0, stream>>>(cursor, spcnt, spcur, l1_sel, l2_res, selT, resT,
                                    spec, embedW, l1_lin, h1p,
                                    l1_rW2, l2_rW2, wfrag);
  k_count<<<EBLK + NBLK, 256, 0, stream>>>(recv, cursor, spec, spcnt);
  k_scanrw<<<1 + (N_EDGES+63)/64, 256, 0, stream>>>(cursor, starts, spcnt, spcur,
        ev, l1_rW1, l2_rW1, wfrag, rw12p, rwBp, shu);
  k_fill <<<EBLK + NBLK, 256, 0, stream>>>(recv, cursor, elist, spec, spcur, nsort);
  k_node1<<<N_NODES/4, 256, 0, stream>>>(send, spec, starts, elist, nsort, shu, rw12p, h1p,
        selT, l1_pw, l1_uw, l1_row, l2_lin, resT, out, outvp, reso);
  k_node2<<<N_NODES/4, 256, 0, stream>>>(send, spec, starts, elist, nsort, shu, rwBp,
        outvp, reso, l2_pw, l2_roW1, l2_roW2, out);
}

// Round 13
// 91.961 us; speedup vs baseline: 1.6587x; 1.6587x over previous
//
#include <hip/hip_runtime.h>
#include <hip/hip_bf16.h>
#include <math.h>

#define N_NODES 10000
#define N_EDGES 100000
#define NCH 64
#define NSPEC 10

typedef __attribute__((ext_vector_type(8))) short short8v;
typedef __attribute__((ext_vector_type(4))) float f32x4;

static __device__ __forceinline__ unsigned short f2bf(float f){
  unsigned u = __float_as_uint(f);
  u += 0x7fff + ((u >> 16) & 1);          // round-to-nearest-even
  return (unsigned short)(u >> 16);
}
static __device__ __forceinline__ float bf2f(unsigned u){
  return __uint_as_float(u << 16);
}
static __device__ __forceinline__ unsigned packbf(float a, float b){
  return (unsigned)f2bf(a) | ((unsigned)f2bf(b) << 16);
}

// ---------- CSR count ----------
__global__ void k_count(const int* __restrict__ recv, int* __restrict__ cnt){
  int i = blockIdx.x*blockDim.x + threadIdx.x;
  if (i < N_EDGES) atomicAdd(&cnt[recv[i]], 1);
}

// ---------- fused prologue: zero cursor | transposes | h1(bf16) | bf16 B-fragments ----------
__global__ __launch_bounds__(256) void k_pre(
  int* __restrict__ cursor,
  const float* __restrict__ sel, const float* __restrict__ resw,
  float* __restrict__ selT, float* __restrict__ resT,
  const int* __restrict__ species, const float* __restrict__ embedW,
  const float* __restrict__ linup, unsigned short* __restrict__ h1p,
  const float* __restrict__ rW2a, const float* __restrict__ rW2b,
  unsigned short* __restrict__ wfrag)
{
  int b = blockIdx.x;
  int tid = threadIdx.x;
  if (b < 40){                                  // zero cursor (10000 ints)
    int i = b*256 + tid;
    if (i < N_NODES) cursor[i] = 0;
  } else if (b < 200){                          // selT/resT transpose (40960 elems)
    int i = (b-40)*256 + tid;
    int s = i >> 12, r = i & 4095, d = r >> 6, c = r & 63;
    int src = s*4096 + c*64 + d;
    selT[i] = sel[src];
    resT[i] = resw[src];
  } else if (b < 2700){                         // h1 = embed[species] @ l1_lin_up (bf16)
    int w = ((b-200)*256 + tid) >> 6;           // 2500 blocks * 4 = 10000
    int lane = tid & 63;
    int sp = __builtin_amdgcn_readfirstlane(species[w]);
    const float* x0 = embedW + sp*NCH;
    float acc = 0.f;
    #pragma unroll
    for (int d = 0; d < NCH; d++) acc += x0[d] * linup[d*NCH + lane];
    h1p[w*NCH + lane] = f2bf(acc);
  } else {                                      // bf16 B-fragments (12288 shorts)
    int i = (b-2700)*256 + tid;
    int slot = i >> 9;                          // 0..23
    int rem  = i & 511;
    int lane = rem >> 3, j = rem & 7;
    int cl = lane & 15, hb = (lane >> 4)*8;
    float v;
    if (slot < 16){
      int t = slot >> 2, f = slot & 3;
      int colofs = f >> 1, off = (f & 1)*32;
      v = rW2a[(hb + off + j)*256 + 4*(t*16 + cl) + colofs];
    } else {
      int s2 = slot - 16;
      int t = s2 >> 1, f = s2 & 1;
      int off = f*32;
      v = rW2b[(hb + off + j)*256 + 4*(t*16 + cl)];
    }
    wfrag[i] = f2bf(v);
  }
}

// ---------- block 0: CSR scan | blocks 1..: MFMA radial GEMM (both layers, 1 barrier) ----------
__global__ __launch_bounds__(256) void k_scanrw(
    int* __restrict__ cnt_cursor, int* __restrict__ starts,
    const float* __restrict__ ev,
    const float* __restrict__ rW1a, const float* __restrict__ rW1b,
    const unsigned short* __restrict__ wfrag,
    unsigned* __restrict__ rw12p, unsigned short* __restrict__ rwBp,
    float4* __restrict__ shu)
{
  __shared__ short s_hid1[64*72];      // [e][h] bf16, row stride 72 (144B)
  __shared__ short s_hid2[64*72];

  int tid = threadIdx.x;

  if (blockIdx.x == 0){
    // coarsened scan: 256 threads, 40 nodes each
    int* stot = (int*)s_hid1;
    int base = tid*40;
    int loc[40];
    int sum = 0;
    #pragma unroll
    for (int j = 0; j < 40; j++){
      int i = base + j;
      int v = (i < N_NODES) ? cnt_cursor[i] : 0;
      loc[j] = sum; sum += v;
    }
    stot[tid] = sum;
    __syncthreads();
    for (int off = 1; off < 256; off <<= 1){
      int t = (tid >= off) ? stot[tid-off] : 0;
      __syncthreads();
      stot[tid] += t;
      __syncthreads();
    }
    int excl = stot[tid] - sum;
    #pragma unroll
    for (int j = 0; j < 40; j++){
      int i = base + j;
      if (i < N_NODES){ int st = excl + loc[j]; starts[i] = st; cnt_cursor[i] = st; }
    }
    if (tid == 255) starts[N_NODES] = stot[255];
    return;
  }

  int e0 = (blockIdx.x-1)*64;
  int lane = tid & 63;
  int w = __builtin_amdgcn_readfirstlane(tid >> 6);    // wave id 0..3

  // geometry + bessel for edge e0+lane (4-way redundant across waves)
  int e = e0 + lane;
  bool act = (e < N_EDGES);
  float ex = 0.f, ey = 0.f, ez = 1.f;
  if (act){ ex = ev[e*3+0]; ey = ev[e*3+1]; ez = ev[e*3+2]; }
  float r = sqrtf(ex*ex + ey*ey + ez*ez + 1e-12f);
  float rinv = 1.0f / r;
  float u = r * 0.2f;
  float env = 0.f;
  if (u < 1.f){ float om = 1.f - u; env = om*om*(1.f + 2.f*u); }
  float pref = 0.6324555320336759f * rinv * env;       // sqrt(2/5)
  float rad[8];
  #pragma unroll
  for (int b = 0; b < 8; b++)
    rad[b] = pref * __sinf((float)(b+1) * 3.14159265358979f * u);
  if (w == 0 && act) shu[e] = make_float4(ex*rinv, ey*rinv, ez*rinv, 0.f);

  // hid for both layers (16 h per wave each), one barrier total
  {
    short8v hv0, hv1, gv0, gv1;
    #pragma unroll
    for (int j = 0; j < 16; j++){
      int h = w*16 + j;
      float a1 = 0.f, a2 = 0.f;
      #pragma unroll
      for (int b = 0; b < 8; b++){
        a1 += rad[b] * rW1a[b*64 + h];               // uniform -> s_load
        a2 += rad[b] * rW1b[b*64 + h];
      }
      float hd1 = a1 / (1.f + __expf(-a1));
      float hd2 = a2 / (1.f + __expf(-a2));
      unsigned short q1 = f2bf(hd1), q2 = f2bf(hd2);
      if (j < 8){ hv0[j] = (short)q1; gv0[j] = (short)q2; }
      else      { hv1[j-8] = (short)q1; gv1[j-8] = (short)q2; }
    }
    *(short8v*)&s_hid1[lane*72 + w*16]     = hv0;
    *(short8v*)&s_hid1[lane*72 + w*16 + 8] = hv1;
    *(short8v*)&s_hid2[lane*72 + w*16]     = gv0;
    *(short8v*)&s_hid2[lane*72 + w*16 + 8] = gv1;
  }
  __syncthreads();

  int cl = lane & 15;                 // col within 16-tile
  int hb = (lane >> 4) * 8;           // k base within 32-step
  int rowq = (lane >> 4) * 4;         // D row base

  short8v a0  = *(short8v*)&s_hid1[(w*16 + cl)*72 + hb];
  short8v a1  = *(short8v*)&s_hid1[(w*16 + cl)*72 + hb + 32];
  short8v c0f = *(short8v*)&s_hid2[(w*16 + cl)*72 + hb];
  short8v c1f = *(short8v*)&s_hid2[(w*16 + cl)*72 + hb + 32];

  const short8v* wf1 = (const short8v*)wfrag;           // 16*64 frags
  const short8v* wf2 = ((const short8v*)wfrag) + 1024;  // 8*64 frags

  f32x4 ax[4], ay[4], bc[4];
  #pragma unroll
  for (int t = 0; t < 4; t++){
    ax[t] = (f32x4)(0.f); ay[t] = (f32x4)(0.f); bc[t] = (f32x4)(0.f);
  }
  #pragma unroll
  for (int t = 0; t < 4; t++){
    short8v bx0 = wf1[(t*4+0)*64 + lane];   // coalesced 16B/lane
    short8v bx1 = wf1[(t*4+1)*64 + lane];
    short8v by0 = wf1[(t*4+2)*64 + lane];
    short8v by1 = wf1[(t*4+3)*64 + lane];
    short8v b20 = wf2[(t*2+0)*64 + lane];
    short8v b21 = wf2[(t*2+1)*64 + lane];
    ax[t] = __builtin_amdgcn_mfma_f32_16x16x32_bf16(a0, bx0, ax[t], 0, 0, 0);
    ax[t] = __builtin_amdgcn_mfma_f32_16x16x32_bf16(a1, bx1, ax[t], 0, 0, 0);
    ay[t] = __builtin_amdgcn_mfma_f32_16x16x32_bf16(a0, by0, ay[t], 0, 0, 0);
    ay[t] = __builtin_amdgcn_mfma_f32_16x16x32_bf16(a1, by1, ay[t], 0, 0, 0);
    bc[t] = __builtin_amdgcn_mfma_f32_16x16x32_bf16(c0f, b20, bc[t], 0, 0, 0);
    bc[t] = __builtin_amdgcn_mfma_f32_16x16x32_bf16(c1f, b21, bc[t], 0, 0, 0);
  }
  #pragma unroll
  for (int t = 0; t < 4; t++){
    #pragma unroll
    for (int i = 0; i < 4; i++){
      int er = e0 + w*16 + rowq + i;
      if (er < N_EDGES){
        rw12p[(size_t)er*64 + t*16 + cl] = packbf(ax[t][i], ay[t][i]);
        rwBp [(size_t)er*64 + t*16 + cl] = f2bf(bc[t][i]);
      }
    }
  }
}

__global__ void k_fill(const int* __restrict__ recv, int* __restrict__ cursor, int* __restrict__ elist){
  int i = blockIdx.x*blockDim.x + threadIdx.x;
  if (i < N_EDGES){ int pos = atomicAdd(&cursor[recv[i]], 1); elist[pos] = i; }
}

// ---------- pass-1 gather + node transforms (1 wave per node, 4-deep prefetch) ----------
__global__ __launch_bounds__(256) void k_node1(
  const int* __restrict__ senders, const int* __restrict__ species,
  const int* __restrict__ starts, const int* __restrict__ elist,
  const float4* __restrict__ shu,
  const unsigned* __restrict__ rw12p, const unsigned short* __restrict__ h1p,
  const float* __restrict__ selT,
  const float* __restrict__ pw, const float* __restrict__ uwv,
  const float* __restrict__ row,
  const float* __restrict__ linup2, const float* __restrict__ resT,
  float* __restrict__ out,
  uint2* __restrict__ outvp, float* __restrict__ reso)
{
  int lane  = threadIdx.x & 63;
  int wslot = threadIdx.x >> 6;
  int n = blockIdx.x*4 + wslot;          // grid exact: 2500*4 = 10000
  __shared__ float4 sacc[4][64];

  int s0 = __builtin_amdgcn_readfirstlane(starts[n]);
  int s1 = __builtin_amdgcn_readfirstlane(starts[n+1]);
  int sp = __builtin_amdgcn_readfirstlane(species[n]);

  float acc0 = 0.f, acc1 = 0.f, acc2 = 0.f, acc3 = 0.f;
  for (int base = s0; base < s1; base += 64){
    int m = min(64, s1 - base);
    int e_l = 0, snd_l = 0;
    if (lane < m){
      e_l   = elist[base + lane];
      snd_l = senders[e_l];
    }
    for (int t = 0; t < m; t += 4){
      int i0 = t;
      int i1 = min(t+1, m-1), i2 = min(t+2, m-1), i3 = min(t+3, m-1);
      float w1 = (t+1 < m) ? 1.f : 0.f;
      float w2 = (t+2 < m) ? 1.f : 0.f;
      float w3 = (t+3 < m) ? 1.f : 0.f;
      int e0i = __builtin_amdgcn_readfirstlane(__shfl(e_l, i0, 64));
      int s0i = __builtin_amdgcn_readfirstlane(__shfl(snd_l, i0, 64));
      int e1i = __builtin_amdgcn_readfirstlane(__shfl(e_l, i1, 64));
      int s1i = __builtin_amdgcn_readfirstlane(__shfl(snd_l, i1, 64));
      int e2i = __builtin_amdgcn_readfirstlane(__shfl(e_l, i2, 64));
      int s2i = __builtin_amdgcn_readfirstlane(__shfl(snd_l, i2, 64));
      int e3i = __builtin_amdgcn_readfirstlane(__shfl(e_l, i3, 64));
      int s3i = __builtin_amdgcn_readfirstlane(__shfl(snd_l, i3, 64));
      unsigned p0 = rw12p[(size_t)e0i*64 + lane];
      unsigned p1 = rw12p[(size_t)e1i*64 + lane];
      unsigned p2 = rw12p[(size_t)e2i*64 + lane];
      unsigned p3 = rw12p[(size_t)e3i*64 + lane];
      float h0 = bf2f(h1p[s0i*64 + lane]);
      float h1v = bf2f(h1p[s1i*64 + lane]) * w1;
      float h2v = bf2f(h1p[s2i*64 + lane]) * w2;
      float h3v = bf2f(h1p[s3i*64 + lane]) * w3;
      float4 v0 = shu[e0i];
      float4 v1 = shu[e1i];
      float4 v2 = shu[e2i];
      float4 v3 = shu[e3i];
      acc0 += bf2f(p0 & 0xffffu)*h0;  float m0 = bf2f(p0 >> 16)*h0;
      acc1 += m0*v0.x; acc2 += m0*v0.y; acc3 += m0*v0.z;
      acc0 += bf2f(p1 & 0xffffu)*h1v; float m1 = bf2f(p1 >> 16)*h1v;
      acc1 += m1*v1.x; acc2 += m1*v1.y; acc3 += m1*v1.z;
      acc0 += bf2f(p2 & 0xffffu)*h2v; float m2 = bf2f(p2 >> 16)*h2v;
      acc1 += m2*v2.x; acc2 += m2*v2.y; acc3 += m2*v2.z;
      acc0 += bf2f(p3 & 0xffffu)*h3v; float m3 = bf2f(p3 >> 16)*h3v;
      acc1 += m3*v3.x; acc2 += m3*v3.y; acc3 += m3*v3.z;
    }
  }
  const float c10 = 0.1f;                      // 1/AVG_NEIGH
  const float c13 = 0.17320508075688773f;      // sqrt(3)/10
  sacc[wslot][lane] = make_float4(acc0*c10, acc1*c13, acc2*c13, acc3*c13);
  asm volatile("s_waitcnt lgkmcnt(0)" ::: "memory");

  // feats[c,k] = sum_d selW[c,d] * agg[d,k]
  const float* selp = selT + sp*4096;
  float f0 = 0.f, f1 = 0.f, f2 = 0.f, f3 = 0.f;
  #pragma unroll 8
  for (int d = 0; d < 64; d++){
    float wv = selp[d*64 + lane];
    float4 a = sacc[wslot][d];
    f0 += wv*a.x; f1 += wv*a.y; f2 += wv*a.z; f3 += wv*a.w;
  }

  float s = f0;
  const float* pwp = pw  + sp*192;
  const float* uwp = uwv + sp*192;
  float pw0 = pwp[lane], pw1 = pwp[64+lane], pw2 = pwp[128+lane];
  float uw0 = uwp[lane], uw1 = uwp[64+lane], uw2 = uwp[128+lane];
  float ss = s*s;
  float o0  = pw0*s + pw1*ss + pw2*ss*s;
  float uco = uw0 + uw1*s + uw2*ss;

  // ro1 = sum_c o0[c]*row[c]
  float rv = o0 * row[lane];
  #pragma unroll
  for (int off = 32; off >= 1; off >>= 1) rv += __shfl_xor(rv, off, 64);
  if (lane == 0) out[n*2 + 0] = rv;

  // stage o0, compute h2 and res
  float* so = reinterpret_cast<float*>(&sacc[wslot][0]);
  asm volatile("s_waitcnt lgkmcnt(0)" ::: "memory");
  so[lane] = o0;
  asm volatile("s_waitcnt lgkmcnt(0)" ::: "memory");

  float hh = 0.f, rr = 0.f;
  const float* resp = resT + sp*4096;
  #pragma unroll 8
  for (int d = 0; d < 64; d++){
    float od = so[d];
    hh += od * linup2[d*64 + lane];
    rr += od * resp[d*64 + lane];
  }
  uint2 op;
  op.x = packbf(uco*f1, uco*f2);
  op.y = packbf(uco*f3, hh);
  outvp[n*64 + lane] = op;
  reso[n*64 + lane] = rr;
}

// ---------- pass-2 gather + readout (1 wave per node, 4-deep prefetch) ----------
__global__ __launch_bounds__(256) void k_node2(
  const int* __restrict__ senders, const int* __restrict__ species,
  const int* __restrict__ starts, const int* __restrict__ elist,
  const float4* __restrict__ shu,
  const unsigned short* __restrict__ rwBp,
  const uint2* __restrict__ outvp, const float* __restrict__ reso,
  const float* __restrict__ pw2,
  const float* __restrict__ roW1, const float* __restrict__ roW2,
  float* __restrict__ out)
{
  int lane  = threadIdx.x & 63;
  int wslot = threadIdx.x >> 6;
  int n = blockIdx.x*4 + wslot;
  __shared__ float sout[4][64];

  int s0 = __builtin_amdgcn_readfirstlane(starts[n]);
  int s1 = __builtin_amdgcn_readfirstlane(starts[n+1]);
  int sp = __builtin_amdgcn_readfirstlane(species[n]);

  float acc = 0.f;
  for (int base = s0; base < s1; base += 64){
    int m = min(64, s1 - base);
    int e_l = 0, snd_l = 0;
    if (lane < m){
      e_l   = elist[base + lane];
      snd_l = senders[e_l];
    }
    for (int t = 0; t < m; t += 4){
      int i0 = t;
      int i1 = min(t+1, m-1), i2 = min(t+2, m-1), i3 = min(t+3, m-1);
      float w1 = (t+1 < m) ? 1.f : 0.f;
      float w2 = (t+2 < m) ? 1.f : 0.f;
      float w3 = (t+3 < m) ? 1.f : 0.f;
      int e0i = __builtin_amdgcn_readfirstlane(__shfl(e_l, i0, 64));
      int s0i = __builtin_amdgcn_readfirstlane(__shfl(snd_l, i0, 64));
      int e1i = __builtin_amdgcn_readfirstlane(__shfl(e_l, i1, 64));
      int s1i = __builtin_amdgcn_readfirstlane(__shfl(snd_l, i1, 64));
      int e2i = __builtin_amdgcn_readfirstlane(__shfl(e_l, i2, 64));
      int s2i = __builtin_amdgcn_readfirstlane(__shfl(snd_l, i2, 64));
      int e3i = __builtin_amdgcn_readfirstlane(__shfl(e_l, i3, 64));
      int s3i = __builtin_amdgcn_readfirstlane(__shfl(snd_l, i3, 64));
      float r0 = bf2f(rwBp[(size_t)e0i*64 + lane]);
      float r1 = bf2f(rwBp[(size_t)e1i*64 + lane]) * w1;
      float r2 = bf2f(rwBp[(size_t)e2i*64 + lane]) * w2;
      float r3 = bf2f(rwBp[(size_t)e3i*64 + lane]) * w3;
      uint2 o0v = outvp[s0i*64 + lane];
      uint2 o1v = outvp[s1i*64 + lane];
      uint2 o2v = outvp[s2i*64 + lane];
      uint2 o3v = outvp[s3i*64 + lane];
      float4 v0 = shu[e0i];
      float4 v1 = shu[e1i];
      float4 v2 = shu[e2i];
      float4 v3 = shu[e3i];
      acc += r0 * (bf2f(o0v.y >> 16) + bf2f(o0v.x & 0xffffu)*v0.x
                   + bf2f(o0v.x >> 16)*v0.y + bf2f(o0v.y & 0xffffu)*v0.z);
      acc += r1 * (bf2f(o1v.y >> 16) + bf2f(o1v.x & 0xffffu)*v1.x
                   + bf2f(o1v.x >> 16)*v1.y + bf2f(o1v.y & 0xffffu)*v1.z);
      acc += r2 * (bf2f(o2v.y >> 16) + bf2f(o2v.x & 0xffffu)*v2.x
                   + bf2f(o2v.x >> 16)*v2.y + bf2f(o2v.y & 0xffffu)*v2.z);
      acc += r3 * (bf2f(o3v.y >> 16) + bf2f(o3v.x & 0xffffu)*v3.x
                   + bf2f(o3v.x >> 16)*v3.y + bf2f(o3v.y & 0xffffu)*v3.z);
    }
  }
  float s2 = acc * 0.1f;
  const float* p2 = pw2 + sp*192;
  float q0 = p2[lane], q1 = p2[64+lane], q2 = p2[128+lane];
  float s2s = s2*s2;
  float o2 = q0*s2 + q1*s2s + q2*s2s*s2 + reso[n*64 + lane];

  sout[wslot][lane] = o2;
  asm volatile("s_waitcnt lgkmcnt(0)" ::: "memory");

  // ro2 = silu(out2 @ roW1) @ roW2
  int j = lane & 15, g = lane >> 4;
  float qp = 0.f;
  #pragma unroll
  for (int t = 0; t < 16; t++){
    int c = g*16 + t;
    qp += sout[wslot][c] * roW1[c*16 + j];
  }
  qp += __shfl_xor(qp, 16, 64);
  qp += __shfl_xor(qp, 32, 64);
  float sil = qp / (1.f + __expf(-qp));
  float contrib = sil * roW2[j];
  contrib += __shfl_xor(contrib, 1, 64);
  contrib += __shfl_xor(contrib, 2, 64);
  contrib += __shfl_xor(contrib, 4, 64);
  contrib += __shfl_xor(contrib, 8, 64);
  if (lane == 0) out[n*2 + 1] = contrib;
}

extern "C" void kernel_launch(void* const* d_in, const int* in_sizes, int n_in,
                              void* d_out, int out_size, void* d_ws, size_t ws_size,
                              hipStream_t stream)
{
  const float* ev     = (const float*)d_in[0];
  const int*   spec   = (const int*)  d_in[1];
  const int*   send   = (const int*)  d_in[2];
  const int*   recv   = (const int*)  d_in[3];
  const float* embedW = (const float*)d_in[4];
  const float* l1_lin = (const float*)d_in[5];
  const float* l1_rW1 = (const float*)d_in[6];
  const float* l1_rW2 = (const float*)d_in[7];
  const float* l1_sel = (const float*)d_in[8];
  const float* l1_pw  = (const float*)d_in[9];
  const float* l1_uw  = (const float*)d_in[10];
  const float* l1_row = (const float*)d_in[11];
  const float* l2_lin = (const float*)d_in[12];
  const float* l2_rW1 = (const float*)d_in[13];
  const float* l2_rW2 = (const float*)d_in[14];
  const float* l2_res = (const float*)d_in[15];
  const float* l2_pw  = (const float*)d_in[16];
  const float* l2_roW1= (const float*)d_in[17];
  const float* l2_roW2= (const float*)d_in[18];
  float* out = (float*)d_out;

  char* w = (char*)d_ws;
  unsigned*       rw12p = (unsigned*)w;       w += (size_t)N_EDGES*64*4;  // 25.6 MB
  unsigned short* rwBp  = (unsigned short*)w; w += (size_t)N_EDGES*64*2;  // 12.8 MB
  unsigned short* h1p   = (unsigned short*)w; w += (size_t)N_NODES*64*2;  // 1.28 MB
  uint2*  outvp = (uint2*)w;  w += (size_t)N_NODES*64*8;                  // 5.12 MB
  float*  reso  = (float*)w;  w += (size_t)N_NODES*64*4;
  float*  selT  = (float*)w;  w += (size_t)NSPEC*4096*4;
  float*  resT  = (float*)w;  w += (size_t)NSPEC*4096*4;
  float4* shu   = (float4*)w; w += (size_t)N_EDGES*16;
  unsigned short* wfrag = (unsigned short*)w; w += 12288*2;
  int* starts = (int*)w;      w += (size_t)(N_NODES+1)*4;
  int* cursor = (int*)w;      w += (size_t)N_NODES*4;
  int* elist  = (int*)w;      w += (size_t)N_EDGES*4;

  k_pre  <<<2748, 256, 0, stream>>>(cursor, l1_sel, l2_res, selT, resT,
                                    spec, embedW, l1_lin, h1p,
                                    l1_rW2, l2_rW2, wfrag);
  k_count<<<(N_EDGES+255)/256, 256, 0, stream>>>(recv, cursor);
  k_scanrw<<<1 + (N_EDGES+63)/64, 256, 0, stream>>>(cursor, starts,
        ev, l1_rW1, l2_rW1, wfrag, rw12p, rwBp, shu);
  k_fill <<<(N_EDGES+255)/256, 256, 0, stream>>>(recv, cursor, elist);
  k_node1<<<N_NODES/4, 256, 0, stream>>>(send, spec, starts, elist, shu, rw12p, h1p,
        selT, l1_pw, l1_uw, l1_row, l2_lin, resT, out, outvp, reso);
  k_node2<<<N_NODES/4, 256, 0, stream>>>(send, spec, starts, elist, shu, rwBp,
        outvp, reso, l2_pw, l2_roW1, l2_roW2, out);
}